// Round 13
// baseline (82.613 us; speedup 1.0000x reference)
//
#include <hip/hip_runtime.h>
#include <hip/hip_bf16.h>
#include <math.h>

#define C 64
#define B 8
#define HW 65536   // 256*256
#define NMID 17
#define NEXP 4
#define TEMP 34.0f
#define XSTR 33    // LDS row stride in dwords (odd -> conflict-free)
#define PX 128     // px tile per block

typedef __attribute__((ext_vector_type(8))) short bf16x8;
typedef __attribute__((ext_vector_type(4))) float f32x4;

// ---------------- Kernel 1: global average pool per (b,c) plane ----------------
__global__ __launch_bounds__(256) void pool_kernel(const float* __restrict__ x,
                                                   float* __restrict__ pooled) {
    const int plane = blockIdx.x;                       // 0..511  == b*64 + c
    const float4* xp = (const float4*)(x + (size_t)plane * HW);
    float s = 0.0f;
    #pragma unroll 4
    for (int it = threadIdx.x; it < HW / 4; it += 256) {
        float4 v = xp[it];
        s += (v.x + v.y) + (v.z + v.w);
    }
    #pragma unroll
    for (int off = 32; off > 0; off >>= 1) s += __shfl_down(s, off);
    __shared__ float wsum[4];
    const int wid = threadIdx.x >> 6;
    if ((threadIdx.x & 63) == 0) wsum[wid] = s;
    __syncthreads();
    if (threadIdx.x == 0) {
        float t = (wsum[0] + wsum[1]) + (wsum[2] + wsum[3]);
        pooled[plane] = t * (1.0f / (float)HW);
    }
}

// ------- Kernel 2: attention (MLP+softmax) + mixed W (bf16, [o][k]) + bias -----
__global__ __launch_bounds__(256) void attn_mix_kernel(const float* __restrict__ pooled,
                                                       const float* __restrict__ fc1_w,
                                                       const float* __restrict__ fc2_w,
                                                       const float* __restrict__ fc2_b,
                                                       const float* __restrict__ ew,
                                                       const float* __restrict__ eb,
                                                       unsigned short* __restrict__ wobf, // [B][o][k] bf16
                                                       float* __restrict__ bmix) {        // [B][o]
    const int b = blockIdx.x;
    const int tid = threadIdx.x;
    __shared__ float pooled_s[C];
    __shared__ float h_s[NMID];
    __shared__ float lg_s[NEXP];
    __shared__ float attn_s[NEXP];

    if (tid < C) pooled_s[tid] = pooled[b * C + tid];
    __syncthreads();

    if (tid < NMID) {
        float s = 0.0f;
        #pragma unroll
        for (int c = 0; c < C; ++c) s += pooled_s[c] * fc1_w[tid * C + c];
        h_s[tid] = fmaxf(s, 0.0f);
    }
    __syncthreads();

    if (tid < NEXP) {
        float s = fc2_b[tid];
        #pragma unroll
        for (int m = 0; m < NMID; ++m) s += h_s[m] * fc2_w[tid * NMID + m];
        lg_s[tid] = s * (1.0f / TEMP);
    }
    __syncthreads();

    if (tid == 0) {
        float mx = fmaxf(fmaxf(lg_s[0], lg_s[1]), fmaxf(lg_s[2], lg_s[3]));
        float e0 = expf(lg_s[0] - mx);
        float e1 = expf(lg_s[1] - mx);
        float e2 = expf(lg_s[2] - mx);
        float e3 = expf(lg_s[3] - mx);
        float inv = 1.0f / (e0 + e1 + e2 + e3);
        attn_s[0] = e0 * inv; attn_s[1] = e1 * inv;
        attn_s[2] = e2 * inv; attn_s[3] = e3 * inv;
    }
    __syncthreads();

    const float a0 = attn_s[0], a1 = attn_s[1], a2 = attn_s[2], a3 = attn_s[3];

    // wobf[b][o][k] = bf16( sum_e attn[e] * ew[e][o][k] )
    #pragma unroll
    for (int k4 = 0; k4 < (C * C) / 256; ++k4) {
        const int idx = k4 * 256 + tid;                  // = o*64 + k, coalesced
        float s = a0 * ew[0 * C * C + idx] + a1 * ew[1 * C * C + idx]
                + a2 * ew[2 * C * C + idx] + a3 * ew[3 * C * C + idx];
        __hip_bfloat16 hb = __float2bfloat16(s);
        wobf[b * C * C + idx] = *reinterpret_cast<unsigned short*>(&hb);
    }
    if (tid < C) {
        float s = a0 * eb[0 * C + tid] + a1 * eb[1 * C + tid]
                + a2 * eb[2 * C + tid] + a3 * eb[3 * C + tid];
        bmix[b * C + tid] = s;
    }
}

// ---------------- Kernel 3: per-sample 1x1 conv via bf16 MFMA ------------------
// Block tile: 64 o x 128 px, 4 waves (each wave: 64 o x 32 px = 4x2 fragments).
// Fragment k-mapping (verified R7): k = ks*32 + 16*(j>>2) + 4*lg + (j&3);
// C/D: col = l&15 (px), row = (l>>4)*4 + reg (o).
// Stores: NONTEMPORAL in (m,r,n) order — single-change test vs R10 (cached,
// same order): does NT avoid L3 pollution (keep x resident for its 2nd read)
// without breaking write-combining, now that the order is right?
__global__ __launch_bounds__(256, 5) void conv_mfma(const float* __restrict__ x,
                                                    const unsigned short* __restrict__ wobf,
                                                    const float* __restrict__ bmix,
                                                    float* __restrict__ out) {
    const int b = blockIdx.y;
    const int px0 = blockIdx.x * PX;
    const int tid = threadIdx.x;

    __shared__ unsigned short xlds[PX * (2 * XSTR)];    // [px][k], row stride 66 bf16
    __shared__ unsigned short wlds[64 * (2 * XSTR)];    // [o][k]

    // ---- stage W tile: 2048 dwords, global [o][k] -> LDS [o][k] ----
    {
        const unsigned int* wsrc = (const unsigned int*)(wobf + b * C * C);
        unsigned int* wd = (unsigned int*)wlds;
        #pragma unroll
        for (int j = 0; j < 8; ++j) {
            const int g = j * 256 + tid;                 // dword id; o = g>>5, m = g&31
            wd[(g >> 5) * XSTR + (g & 31)] = wsrc[g];
        }
    }

    // ---- stage X tile: global [k][px] fp32 -> LDS [px][k] bf16 (transpose) ----
    {
        const int kr = tid >> 6;                         // k row within group of 4
        const int s = tid & 63;                          // float2 index within 128-px row
        #pragma unroll 4
        for (int it = 0; it < 16; ++it) {
            const int k = it * 4 + kr;
            float2 v = ((const float2*)(x + (size_t)(b * C + k) * HW + px0))[s];
            __hip_bfloat16 h0 = __float2bfloat16(v.x);
            __hip_bfloat16 h1 = __float2bfloat16(v.y);
            xlds[(2 * s    ) * (2 * XSTR) + k] = *reinterpret_cast<unsigned short*>(&h0);
            xlds[(2 * s + 1) * (2 * XSTR) + k] = *reinterpret_cast<unsigned short*>(&h1);
        }
    }
    __syncthreads();

    const int wv = tid >> 6;                             // wave 0..3 -> 32-px slice
    const int lr = tid & 15;
    const int lg = (tid & 63) >> 4;

    // acc init with bias (row o = m*16 + lg*4 + r)
    f32x4 acc[4][2];
    #pragma unroll
    for (int m = 0; m < 4; ++m) {
        f32x4 bv;
        #pragma unroll
        for (int r = 0; r < 4; ++r) bv[r] = bmix[b * C + m * 16 + lg * 4 + r];
        #pragma unroll
        for (int n = 0; n < 2; ++n) acc[m][n] = bv;
    }

    const unsigned int* xw = (const unsigned int*)xlds;
    const unsigned int* ww = (const unsigned int*)wlds;

    #pragma unroll
    for (int ks = 0; ks < 2; ++ks) {
        bf16x8 af[4], bxf[2];
        #pragma unroll
        for (int m = 0; m < 4; ++m) {
            const int off = (m * 16 + lr) * XSTR + ks * 16 + lg * 2;
            union { unsigned int u[4]; bf16x8 v; } t;
            t.u[0] = ww[off];     t.u[1] = ww[off + 1];
            t.u[2] = ww[off + 8]; t.u[3] = ww[off + 9];
            af[m] = t.v;
        }
        #pragma unroll
        for (int n = 0; n < 2; ++n) {
            const int off = (wv * 32 + n * 16 + lr) * XSTR + ks * 16 + lg * 2;
            union { unsigned int u[4]; bf16x8 v; } t;
            t.u[0] = xw[off];     t.u[1] = xw[off + 1];
            t.u[2] = xw[off + 8]; t.u[3] = xw[off + 9];
            bxf[n] = t.v;
        }
        #pragma unroll
        for (int m = 0; m < 4; ++m)
            #pragma unroll
            for (int n = 0; n < 2; ++n)
                acc[m][n] = __builtin_amdgcn_mfma_f32_16x16x32_bf16(af[m], bxf[n], acc[m][n], 0, 0, 0);
    }

    // ---- store: NONTEMPORAL, (m,r,n) order (two 64B halves per o-row
    //      back-to-back; 4 waves cover the full 128B lines) ----
    #pragma unroll
    for (int m = 0; m < 4; ++m) {
        float* opm = out + (size_t)(b * C + m * 16 + lg * 4) * HW + px0 + wv * 32 + lr;
        #pragma unroll
        for (int r = 0; r < 4; ++r)
            #pragma unroll
            for (int n = 0; n < 2; ++n)
                __builtin_nontemporal_store(acc[m][n][r], opm + (size_t)r * HW + n * 16);
    }
}

extern "C" void kernel_launch(void* const* d_in, const int* in_sizes, int n_in,
                              void* d_out, int out_size, void* d_ws, size_t ws_size,
                              hipStream_t stream) {
    const float* x     = (const float*)d_in[0];
    const float* fc1_w = (const float*)d_in[1];
    const float* fc2_w = (const float*)d_in[2];
    const float* fc2_b = (const float*)d_in[3];
    const float* ew    = (const float*)d_in[4];
    const float* eb    = (const float*)d_in[5];
    float* out = (float*)d_out;

    // workspace layout: pooled[512] f32 | bmix[512] f32 | wobf[8*4096] bf16
    float* ws     = (float*)d_ws;
    float* pooled = ws;
    float* bmix   = ws + B * C;
    unsigned short* wobf = (unsigned short*)(ws + 2 * B * C);

    pool_kernel<<<dim3(B * C), dim3(256), 0, stream>>>(x, pooled);
    attn_mix_kernel<<<dim3(B), dim3(256), 0, stream>>>(pooled, fc1_w, fc2_w, fc2_b, ew, eb, wobf, bmix);
    conv_mfma<<<dim3(HW / PX, B), dim3(256), 0, stream>>>(x, wobf, bmix, out);
}

// Round 14
// 70.334 us; speedup vs baseline: 1.1746x; 1.1746x over previous
//
#include <hip/hip_runtime.h>
#include <hip/hip_bf16.h>
#include <math.h>

#define C 64
#define B 8
#define HW 65536   // 256*256
#define NMID 17
#define NEXP 4
#define TEMP 34.0f
#define XSTR 33    // LDS row stride in dwords (odd -> conflict-free)
#define PX 128     // px tile per block

typedef __attribute__((ext_vector_type(8))) short bf16x8;
typedef __attribute__((ext_vector_type(4))) float f32x4;

// ---------------- Kernel 1: global average pool per (b,c) plane ----------------
__global__ __launch_bounds__(256) void pool_kernel(const float* __restrict__ x,
                                                   float* __restrict__ pooled) {
    const int plane = blockIdx.x;                       // 0..511  == b*64 + c
    const float4* xp = (const float4*)(x + (size_t)plane * HW);
    float s = 0.0f;
    #pragma unroll 4
    for (int it = threadIdx.x; it < HW / 4; it += 256) {
        float4 v = xp[it];
        s += (v.x + v.y) + (v.z + v.w);
    }
    #pragma unroll
    for (int off = 32; off > 0; off >>= 1) s += __shfl_down(s, off);
    __shared__ float wsum[4];
    const int wid = threadIdx.x >> 6;
    if ((threadIdx.x & 63) == 0) wsum[wid] = s;
    __syncthreads();
    if (threadIdx.x == 0) {
        float t = (wsum[0] + wsum[1]) + (wsum[2] + wsum[3]);
        pooled[plane] = t * (1.0f / (float)HW);
    }
}

// ------- Kernel 2: attention (MLP+softmax) + mixed W (bf16, [o][k]) + bias -----
__global__ __launch_bounds__(256) void attn_mix_kernel(const float* __restrict__ pooled,
                                                       const float* __restrict__ fc1_w,
                                                       const float* __restrict__ fc2_w,
                                                       const float* __restrict__ fc2_b,
                                                       const float* __restrict__ ew,
                                                       const float* __restrict__ eb,
                                                       unsigned short* __restrict__ wobf, // [B][o][k] bf16
                                                       float* __restrict__ bmix) {        // [B][o]
    const int b = blockIdx.x;
    const int tid = threadIdx.x;
    __shared__ float pooled_s[C];
    __shared__ float h_s[NMID];
    __shared__ float lg_s[NEXP];
    __shared__ float attn_s[NEXP];

    if (tid < C) pooled_s[tid] = pooled[b * C + tid];
    __syncthreads();

    if (tid < NMID) {
        float s = 0.0f;
        #pragma unroll
        for (int c = 0; c < C; ++c) s += pooled_s[c] * fc1_w[tid * C + c];
        h_s[tid] = fmaxf(s, 0.0f);
    }
    __syncthreads();

    if (tid < NEXP) {
        float s = fc2_b[tid];
        #pragma unroll
        for (int m = 0; m < NMID; ++m) s += h_s[m] * fc2_w[tid * NMID + m];
        lg_s[tid] = s * (1.0f / TEMP);
    }
    __syncthreads();

    if (tid == 0) {
        float mx = fmaxf(fmaxf(lg_s[0], lg_s[1]), fmaxf(lg_s[2], lg_s[3]));
        float e0 = expf(lg_s[0] - mx);
        float e1 = expf(lg_s[1] - mx);
        float e2 = expf(lg_s[2] - mx);
        float e3 = expf(lg_s[3] - mx);
        float inv = 1.0f / (e0 + e1 + e2 + e3);
        attn_s[0] = e0 * inv; attn_s[1] = e1 * inv;
        attn_s[2] = e2 * inv; attn_s[3] = e3 * inv;
    }
    __syncthreads();

    const float a0 = attn_s[0], a1 = attn_s[1], a2 = attn_s[2], a3 = attn_s[3];

    // wobf[b][o][k] = bf16( sum_e attn[e] * ew[e][o][k] )
    #pragma unroll
    for (int k4 = 0; k4 < (C * C) / 256; ++k4) {
        const int idx = k4 * 256 + tid;                  // = o*64 + k, coalesced
        float s = a0 * ew[0 * C * C + idx] + a1 * ew[1 * C * C + idx]
                + a2 * ew[2 * C * C + idx] + a3 * ew[3 * C * C + idx];
        __hip_bfloat16 hb = __float2bfloat16(s);
        wobf[b * C * C + idx] = *reinterpret_cast<unsigned short*>(&hb);
    }
    if (tid < C) {
        float s = a0 * eb[0 * C + tid] + a1 * eb[1 * C + tid]
                + a2 * eb[2 * C + tid] + a3 * eb[3 * C + tid];
        bmix[b * C + tid] = s;
    }
}

// ---------------- Kernel 3: per-sample 1x1 conv via bf16 MFMA ------------------
// Block tile: 64 o x 128 px, 4 waves (each wave: 64 o x 32 px = 4x2 fragments).
// Fragment k-mapping (verified R7): k = ks*32 + 16*(j>>2) + 4*lg + (j&3);
// C/D: col = l&15 (px), row = (l>>4)*4 + reg (o).
// Cached stores in (m,r,n) order (NT costs ~11 µs — R9/R13).
// X staged via float4 (16B/lane) — halves staging VMEM instruction count.
__global__ __launch_bounds__(256, 5) void conv_mfma(const float* __restrict__ x,
                                                    const unsigned short* __restrict__ wobf,
                                                    const float* __restrict__ bmix,
                                                    float* __restrict__ out) {
    const int b = blockIdx.y;
    const int px0 = blockIdx.x * PX;
    const int tid = threadIdx.x;

    __shared__ unsigned short xlds[PX * (2 * XSTR)];    // [px][k], row stride 66 bf16
    __shared__ unsigned short wlds[64 * (2 * XSTR)];    // [o][k]

    // ---- stage W tile: 2048 dwords, global [o][k] -> LDS [o][k] ----
    {
        const unsigned int* wsrc = (const unsigned int*)(wobf + b * C * C);
        unsigned int* wd = (unsigned int*)wlds;
        #pragma unroll
        for (int j = 0; j < 8; ++j) {
            const int g = j * 256 + tid;                 // dword id; o = g>>5, m = g&31
            wd[(g >> 5) * XSTR + (g & 31)] = wsrc[g];
        }
    }

    // ---- stage X tile: global [k][px] fp32 -> LDS [px][k] bf16 (transpose) ----
    // float4 loads: 32 lanes cover one 128-px row; 8 k-rows in flight.
    {
        const int kr = tid >> 5;                         // k row within group of 8
        const int s = tid & 31;                          // float4 index within row
        #pragma unroll
        for (int it = 0; it < 8; ++it) {
            const int k = it * 8 + kr;
            float4 v = ((const float4*)(x + (size_t)(b * C + k) * HW + px0))[s];
            __hip_bfloat16 h0 = __float2bfloat16(v.x);
            __hip_bfloat16 h1 = __float2bfloat16(v.y);
            __hip_bfloat16 h2 = __float2bfloat16(v.z);
            __hip_bfloat16 h3 = __float2bfloat16(v.w);
            xlds[(4 * s    ) * (2 * XSTR) + k] = *reinterpret_cast<unsigned short*>(&h0);
            xlds[(4 * s + 1) * (2 * XSTR) + k] = *reinterpret_cast<unsigned short*>(&h1);
            xlds[(4 * s + 2) * (2 * XSTR) + k] = *reinterpret_cast<unsigned short*>(&h2);
            xlds[(4 * s + 3) * (2 * XSTR) + k] = *reinterpret_cast<unsigned short*>(&h3);
        }
    }
    __syncthreads();

    const int wv = tid >> 6;                             // wave 0..3 -> 32-px slice
    const int lr = tid & 15;
    const int lg = (tid & 63) >> 4;

    // acc init with bias (row o = m*16 + lg*4 + r)
    f32x4 acc[4][2];
    #pragma unroll
    for (int m = 0; m < 4; ++m) {
        f32x4 bv;
        #pragma unroll
        for (int r = 0; r < 4; ++r) bv[r] = bmix[b * C + m * 16 + lg * 4 + r];
        #pragma unroll
        for (int n = 0; n < 2; ++n) acc[m][n] = bv;
    }

    const unsigned int* xw = (const unsigned int*)xlds;
    const unsigned int* ww = (const unsigned int*)wlds;

    #pragma unroll
    for (int ks = 0; ks < 2; ++ks) {
        bf16x8 af[4], bxf[2];
        #pragma unroll
        for (int m = 0; m < 4; ++m) {
            const int off = (m * 16 + lr) * XSTR + ks * 16 + lg * 2;
            union { unsigned int u[4]; bf16x8 v; } t;
            t.u[0] = ww[off];     t.u[1] = ww[off + 1];
            t.u[2] = ww[off + 8]; t.u[3] = ww[off + 9];
            af[m] = t.v;
        }
        #pragma unroll
        for (int n = 0; n < 2; ++n) {
            const int off = (wv * 32 + n * 16 + lr) * XSTR + ks * 16 + lg * 2;
            union { unsigned int u[4]; bf16x8 v; } t;
            t.u[0] = xw[off];     t.u[1] = xw[off + 1];
            t.u[2] = xw[off + 8]; t.u[3] = xw[off + 9];
            bxf[n] = t.v;
        }
        #pragma unroll
        for (int m = 0; m < 4; ++m)
            #pragma unroll
            for (int n = 0; n < 2; ++n)
                acc[m][n] = __builtin_amdgcn_mfma_f32_16x16x32_bf16(af[m], bxf[n], acc[m][n], 0, 0, 0);
    }

    // ---- store: plain cached, (m,r,n) order for L2 write-combining ----
    #pragma unroll
    for (int m = 0; m < 4; ++m) {
        float* opm = out + (size_t)(b * C + m * 16 + lg * 4) * HW + px0 + wv * 32 + lr;
        #pragma unroll
        for (int r = 0; r < 4; ++r)
            #pragma unroll
            for (int n = 0; n < 2; ++n)
                opm[(size_t)r * HW + n * 16] = acc[m][n][r];
    }
}

extern "C" void kernel_launch(void* const* d_in, const int* in_sizes, int n_in,
                              void* d_out, int out_size, void* d_ws, size_t ws_size,
                              hipStream_t stream) {
    const float* x     = (const float*)d_in[0];
    const float* fc1_w = (const float*)d_in[1];
    const float* fc2_w = (const float*)d_in[2];
    const float* fc2_b = (const float*)d_in[3];
    const float* ew    = (const float*)d_in[4];
    const float* eb    = (const float*)d_in[5];
    float* out = (float*)d_out;

    // workspace layout: pooled[512] f32 | bmix[512] f32 | wobf[8*4096] bf16
    float* ws     = (float*)d_ws;
    float* pooled = ws;
    float* bmix   = ws + B * C;
    unsigned short* wobf = (unsigned short*)(ws + 2 * B * C);

    pool_kernel<<<dim3(B * C), dim3(256), 0, stream>>>(x, pooled);
    attn_mix_kernel<<<dim3(B), dim3(256), 0, stream>>>(pooled, fc1_w, fc2_w, fc2_b, ew, eb, wobf, bmix);
    conv_mfma<<<dim3(HW / PX, B), dim3(256), 0, stream>>>(x, wobf, bmix, out);
}